// Round 1
// baseline (237.417 us; speedup 1.0000x reference)
//
#include <hip/hip_runtime.h>

#define HW    512
#define OUTW  128
#define NIMG  96                       // 32*3
#define N_HR  (NIMG*HW*HW)             // 25165824
#define N_LR  (NIMG*OUTW*OUTW)         // 1572864
#define NSLOT 256

// PyTorch bicubic kernel, a = -0.75
__device__ __forceinline__ float cubic075(float x){
    float ax = fabsf(x);
    float ax2 = ax*ax, ax3 = ax2*ax;
    const float A = -0.75f;
    float f1 = (A+2.f)*ax3 - (A+3.f)*ax2 + 1.f;
    float f2 = A*ax3 - 5.f*A*ax2 + 8.f*A*ax - 4.f*A;
    return ax <= 1.f ? f1 : (ax < 2.f ? f2 : 0.f);
}

// scale=4 antialiased window: 16 taps at idx offsets -6..9 from 4*o,
// dist = (k-7.5)/4, normalized. Shift-invariant across all outputs.
__device__ __forceinline__ void get_weights(float w[16]){
    float s = 0.f;
#pragma unroll
    for (int k = 0; k < 16; ++k){
        float d = ((float)k - 7.5f) * 0.25f;
        w[k] = cubic075(d);
        s += w[k];
    }
#pragma unroll
    for (int k = 0; k < 16; ++k) w[k] /= s;
}

// reduce a float over a 128-thread block, atomically add (as double) to *slot
__device__ __forceinline__ void reduce128_atomic(float v, double* slot){
#pragma unroll
    for (int off = 32; off > 0; off >>= 1)
        v += __shfl_down(v, off, 64);
    __shared__ float wsum[2];
    const int lane = threadIdx.x & 63, wid = threadIdx.x >> 6;
    if (lane == 0) wsum[wid] = v;
    __syncthreads();
    if (threadIdx.x == 0)
        atomicAdd(slot, (double)(wsum[0] + wsum[1]));
}

__global__ void kinit(double* p){
    p[blockIdx.x * blockDim.x + threadIdx.x] = 0.0;
}

// one input row (512 f32) per block; fused |pred-tgt| partial + horizontal resize
__global__ __launch_bounds__(128) void k1(const float* __restrict__ pred,
                                          const float* __restrict__ tgt,
                                          float* __restrict__ tmp,
                                          double* __restrict__ psum){
    const int gr = blockIdx.x;            // global row: img*512 + h
    const int t  = threadIdx.x;           // 0..127
    __shared__ float row[HW];

    const float4 a = ((const float4*)(pred + (size_t)gr * HW))[t];
    const float4 b = ((const float4*)(tgt  + (size_t)gr * HW))[t];
    ((float4*)row)[t] = a;
    float part = fabsf(a.x-b.x) + fabsf(a.y-b.y) + fabsf(a.z-b.z) + fabsf(a.w-b.w);
    __syncthreads();

    float w[16]; get_weights(w);
    const int base = 4*t - 6;
    float acc = 0.f;
#pragma unroll
    for (int k = 0; k < 16; ++k){
        int x = base + k;
        x = max(0, min(HW-1, x));
        acc += w[k] * row[x];
    }
    tmp[(size_t)gr * OUTW + t] = acc;

    reduce128_atomic(part, &psum[gr & (NSLOT-1)]);
}

// one output row (128 px) per block; vertical resize + |pred_lr - lr_ref| partial
__global__ __launch_bounds__(128) void k2(const float* __restrict__ tmp,
                                          const float* __restrict__ lr,
                                          double* __restrict__ psum){
    const int gor = blockIdx.x;           // img*128 + o
    const int img = gor >> 7, o = gor & 127;
    const int t   = threadIdx.x;          // column p

    float w[16]; get_weights(w);
    const float* T = tmp + (size_t)img * HW * OUTW;
    const int base = 4*o - 6;
    float acc = 0.f;
#pragma unroll
    for (int r = 0; r < 16; ++r){
        int y = max(0, min(HW-1, base + r));
        acc += w[r] * T[y * OUTW + t];
    }
    float part = fabsf(acc - lr[(size_t)gor * OUTW + t]);

    reduce128_atomic(part, &psum[gor & (NSLOT-1)]);
}

__global__ __launch_bounds__(256) void k3(const double* __restrict__ p1,
                                          const double* __restrict__ p2,
                                          float* __restrict__ out){
    const int t = threadIdx.x;
    double v1 = p1[t], v2 = p2[t];
#pragma unroll
    for (int off = 32; off > 0; off >>= 1){
        v1 += __shfl_down(v1, off, 64);
        v2 += __shfl_down(v2, off, 64);
    }
    __shared__ double s1[4], s2[4];
    const int lane = t & 63, wid = t >> 6;
    if (lane == 0){ s1[wid] = v1; s2[wid] = v2; }
    __syncthreads();
    if (t == 0){
        double S1 = s1[0]+s1[1]+s1[2]+s1[3];
        double S2 = s2[0]+s2[1]+s2[2]+s2[3];
        float pix     = (float)(S1 / (double)N_HR);
        float lr_term = (float)(S2 / (double)N_LR);
        float pair    = 0.f;
        float consist = 1.0f * lr_term + 1.0f * pair;   // LAM_LR, LAM_PAIR
        float total   = pix + 0.1f * consist;           // LAM_CONSIST
        out[0] = total; out[1] = pix; out[2] = consist; out[3] = lr_term; out[4] = pair;
    }
}

extern "C" void kernel_launch(void* const* d_in, const int* in_sizes, int n_in,
                              void* d_out, int out_size, void* d_ws, size_t ws_size,
                              hipStream_t stream){
    const float* pred = (const float*)d_in[0];
    const float* tgt  = (const float*)d_in[1];
    const float* lrr  = (const float*)d_in[2];
    // d_in[3] = scale (uniform 4.0) -> static sizes, unused
    float* out = (float*)d_out;

    double* p1  = (double*)d_ws;                 // 256 doubles
    double* p2  = p1 + NSLOT;                    // 256 doubles
    float*  tmp = (float*)((char*)d_ws + 4096);  // 96*512*128 f32 = 25.2 MB

    kinit<<<1, 2*NSLOT, 0, stream>>>(p1);
    k1<<<NIMG*HW,   128, 0, stream>>>(pred, tgt, tmp, p1);
    k2<<<NIMG*OUTW, 128, 0, stream>>>(tmp, lrr, p2);
    k3<<<1, 256, 0, stream>>>(p1, p2, out);
}

// Round 2
// 232.656 us; speedup vs baseline: 1.0205x; 1.0205x over previous
//
#include <hip/hip_runtime.h>

#define HW    512
#define OUTW  128
#define NIMG  96                       // 32*3
#define N_HR  ((long long)NIMG*HW*HW)  // 25165824
#define N_LR  ((long long)NIMG*OUTW*OUTW) // 1572864
#define NSLOT 256

// PyTorch bicubic kernel, a = -0.75
__device__ __forceinline__ float cubic075(float x){
    float ax = fabsf(x);
    float ax2 = ax*ax, ax3 = ax2*ax;
    const float A = -0.75f;
    float f1 = (A+2.f)*ax3 - (A+3.f)*ax2 + 1.f;
    float f2 = A*ax3 - 5.f*A*ax2 + 8.f*A*ax - 4.f*A;
    return ax <= 1.f ? f1 : (ax < 2.f ? f2 : 0.f);
}

// scale=4 antialiased window: 16 taps, dist=(k-7.5)/4, normalized.
// Shift-invariant across all output positions (verified absmax=0.0 in R1).
__device__ __forceinline__ void get_weights(float w[16]){
    float s = 0.f;
#pragma unroll
    for (int k = 0; k < 16; ++k){
        float d = ((float)k - 7.5f) * 0.25f;
        w[k] = cubic075(d);
        s += w[k];
    }
#pragma unroll
    for (int k = 0; k < 16; ++k) w[k] /= s;
}

__global__ void kinit(double* p){
    int i = blockIdx.x * blockDim.x + threadIdx.x;
    if (i < 2*NSLOT) p[i] = 0.0;
}

// Fused: pix |pred-tgt| + separable 4x bicubic-AA resize + |pred_lr - lr| .
// Block = (img, 16 output rows). 256 thr = 4 waves; each wave handles one
// full 512-px input row per iteration (8 cols/lane in registers).
// Horizontal filter via wave shuffles (no LDS). Vertical via 16-row LDS ring.
__global__ __launch_bounds__(256) void kmain(const float* __restrict__ pred,
                                             const float* __restrict__ tgt,
                                             const float* __restrict__ lr,
                                             double* __restrict__ p1,
                                             double* __restrict__ p2){
    const int img = blockIdx.x >> 3;
    const int o0  = (blockIdx.x & 7) << 4;   // first output row of this block
    const int s   = 4*o0 - 6;                // first (unclamped) input row
    const int tid = threadIdx.x;
    const int w   = tid >> 6;                // wave 0..3
    const int l   = tid & 63;                // lane

    __shared__ float  ring[16][128];         // horizontally-filtered rows
    __shared__ double sred[8];

    float wt[16]; get_weights(wt);
    const float* P = pred + (size_t)img * HW * HW;
    const float* T = tgt  + (size_t)img * HW * HW;
    const float* L = lr   + (size_t)img * OUTW * OUTW;

    float pix_acc = 0.f, lr_acc = 0.f;

    // prefetch row for i=0
    int j = w;                                // local input row index
    int hc = min(HW-1, max(0, s + j));
    const float4* rp = (const float4*)(P + (size_t)hc * HW);
    float4 a0 = rp[2*l], a1 = rp[2*l+1];

    for (int i = 0; i < 19; ++i){
        const int jcur = 4*i + w;
        const bool owned = (jcur >= 6 && jcur < 70);
        float4 b0, b1;
        if (owned){
            int hcc = min(HW-1, max(0, s + jcur));
            const float4* tp = (const float4*)(T + (size_t)hcc * HW);
            b0 = tp[2*l]; b1 = tp[2*l+1];
        }
        float p0=a0.x,p1v=a0.y,p2v=a0.z,p3=a0.w,p4=a1.x,p5=a1.y,p6=a1.z,p7=a1.w;

        // prefetch next iteration's pred row
        if (i < 18){
            int jn = 4*(i+1) + w;
            int hn = min(HW-1, max(0, s + jn));
            const float4* rpn = (const float4*)(P + (size_t)hn * HW);
            a0 = rpn[2*l]; a1 = rpn[2*l+1];
        }

        if (owned){
            pix_acc += fabsf(p0-b0.x)+fabsf(p1v-b0.y)+fabsf(p2v-b0.z)+fabsf(p3-b0.w)
                     + fabsf(p4-b1.x)+fabsf(p5-b1.y)+fabsf(p6-b1.z)+fabsf(p7-b1.w);
        }

        // neighbor halo via shuffles: cols 8l-6..8l-1 and 8l+8..8l+13
        float Lm6 = __shfl_up(p2v,1,64), Lm5 = __shfl_up(p3,1,64),
              Lm4 = __shfl_up(p4,1,64),  Lm3 = __shfl_up(p5,1,64),
              Lm2 = __shfl_up(p6,1,64),  Lm1 = __shfl_up(p7,1,64);
        float R8  = __shfl_down(p0,1,64), R9  = __shfl_down(p1v,1,64),
              R10 = __shfl_down(p2v,1,64),R11 = __shfl_down(p3,1,64),
              R12 = __shfl_down(p4,1,64), R13 = __shfl_down(p5,1,64);
        if (l == 0){ Lm6=p0; Lm5=p0; Lm4=p0; Lm3=p0; Lm2=p0; Lm1=p0; }
        if (l == 63){ R8=p7; R9=p7; R10=p7; R11=p7; R12=p7; R13=p7; }

        float w20[20] = {Lm6,Lm5,Lm4,Lm3,Lm2,Lm1,p0,p1v,p2v,p3,p4,p5,p6,p7,
                         R8,R9,R10,R11,R12,R13};
        float out0 = 0.f, out1 = 0.f;
#pragma unroll
        for (int k = 0; k < 16; ++k){
            out0 += wt[k]*w20[k];
            out1 += wt[k]*w20[k+4];
        }
        ring[jcur & 15][2*l]   = out0;
        ring[jcur & 15][2*l+1] = out1;

        __syncthreads();
        if (i >= 3 && tid < 128){
            const int q = i - 3;                 // local output row
            float acc = 0.f;
#pragma unroll
            for (int r = 0; r < 16; ++r)
                acc += wt[r] * ring[(4*q + r) & 15][tid];
            lr_acc += fabsf(acc - L[(size_t)(o0 + q) * OUTW + tid]);
        }
        __syncthreads();   // protect ring rows before next overwrite
    }

    // block reduction -> slotted double atomics
#pragma unroll
    for (int off = 32; off > 0; off >>= 1){
        pix_acc += __shfl_down(pix_acc, off, 64);
        lr_acc  += __shfl_down(lr_acc,  off, 64);
    }
    if (l == 0){ sred[w] = (double)pix_acc; sred[4+w] = (double)lr_acc; }
    __syncthreads();
    if (tid == 0){
        double S1 = sred[0]+sred[1]+sred[2]+sred[3];
        atomicAdd(&p1[blockIdx.x & (NSLOT-1)], S1);
    }
    if (tid == 64){
        double S2 = sred[4]+sred[5]+sred[6]+sred[7];
        atomicAdd(&p2[blockIdx.x & (NSLOT-1)], S2);
    }
}

__global__ __launch_bounds__(256) void k3(const double* __restrict__ p1,
                                          const double* __restrict__ p2,
                                          float* __restrict__ out){
    const int t = threadIdx.x;
    double v1 = p1[t], v2 = p2[t];
#pragma unroll
    for (int off = 32; off > 0; off >>= 1){
        v1 += __shfl_down(v1, off, 64);
        v2 += __shfl_down(v2, off, 64);
    }
    __shared__ double s1[4], s2[4];
    const int lane = t & 63, wid = t >> 6;
    if (lane == 0){ s1[wid] = v1; s2[wid] = v2; }
    __syncthreads();
    if (t == 0){
        double S1 = s1[0]+s1[1]+s1[2]+s1[3];
        double S2 = s2[0]+s2[1]+s2[2]+s2[3];
        float pix     = (float)(S1 / (double)N_HR);
        float lr_term = (float)(S2 / (double)N_LR);
        float pair    = 0.f;
        float consist = 1.0f * lr_term + 1.0f * pair;   // LAM_LR, LAM_PAIR
        float total   = pix + 0.1f * consist;           // LAM_CONSIST
        out[0] = total; out[1] = pix; out[2] = consist; out[3] = lr_term; out[4] = pair;
    }
}

extern "C" void kernel_launch(void* const* d_in, const int* in_sizes, int n_in,
                              void* d_out, int out_size, void* d_ws, size_t ws_size,
                              hipStream_t stream){
    const float* pred = (const float*)d_in[0];
    const float* tgt  = (const float*)d_in[1];
    const float* lrr  = (const float*)d_in[2];
    float* out = (float*)d_out;

    double* p1 = (double*)d_ws;          // 256 doubles
    double* p2 = p1 + NSLOT;             // 256 doubles

    kinit<<<2, 256, 0, stream>>>(p1);
    kmain<<<NIMG*8, 256, 0, stream>>>(pred, tgt, lrr, p1, p2);
    k3<<<1, 256, 0, stream>>>(p1, p2, out);
}

// Round 3
// 229.545 us; speedup vs baseline: 1.0343x; 1.0136x over previous
//
#include <hip/hip_runtime.h>

#define HW    512
#define OUTW  128
#define NIMG  96                          // 32*3
#define N_HR  ((long long)NIMG*HW*HW)     // 25165824
#define N_LR  ((long long)NIMG*OUTW*OUTW) // 1572864
#define NPART (NIMG*32)                   // one slot per wave (4 out rows each)

// PyTorch bicubic kernel, a = -0.75
__device__ __forceinline__ float cubic075(float x){
    float ax = fabsf(x);
    float ax2 = ax*ax, ax3 = ax2*ax;
    const float A = -0.75f;
    float f1 = (A+2.f)*ax3 - (A+3.f)*ax2 + 1.f;
    float f2 = A*ax3 - 5.f*A*ax2 + 8.f*A*ax - 4.f*A;
    return ax <= 1.f ? f1 : (ax < 2.f ? f2 : 0.f);
}

// scale=4 antialiased window: 16 taps, dist=(k-7.5)/4, normalized.
// Shift-invariant across all output positions (verified absmax=0.0 in R1/R2).
__device__ __forceinline__ void get_weights(float w[16]){
    float s = 0.f;
#pragma unroll
    for (int k = 0; k < 16; ++k){
        float d = ((float)k - 7.5f) * 0.25f;
        w[k] = cubic075(d);
        s += w[k];
    }
#pragma unroll
    for (int k = 0; k < 16; ++k) w[k] /= s;
}

// Fully fused, barrier-free. One WAVE = (img, 4 consecutive output rows).
// Wave reads input rows 16g-6 .. 16g+21 (28 rows, clamped), h-filters each
// row in-register via shuffles (8 px/lane -> out cols 2l,2l+1), and keeps
// 4x2 vertical accumulators in VGPRs. Pix term: wave owns input rows
// 16g..16g+15 (iteration window i in [6,22)). Depth-2 rotating prefetch on
// both pred and tgt streams. No LDS, no atomics.
__global__ __launch_bounds__(256) void kmain(const float* __restrict__ pred,
                                             const float* __restrict__ tgt,
                                             const float* __restrict__ lr,
                                             double* __restrict__ part){
    const int img = blockIdx.x >> 3;
    const int tid = threadIdx.x;
    const int w   = tid >> 6;                 // wave in block 0..3
    const int l   = tid & 63;
    const int gw  = ((blockIdx.x & 7) << 2) + w;  // wave in image 0..31
    const int o0  = gw << 2;                  // first output row
    const int s   = (gw << 4) - 6;            // first (unclamped) input row

    float wt[16]; get_weights(wt);
    const float* P = pred + (size_t)img * (HW*HW);
    const float* T = tgt  + (size_t)img * (HW*HW);
    const float* L = lr   + (size_t)img * (OUTW*OUTW);

    float acc[4][2] = {{0.f,0.f},{0.f,0.f},{0.f,0.f},{0.f,0.f}};
    float pix_acc = 0.f, lr_acc = 0.f;

    // depth-2 rotating prefetch: (c)=row i, (n)=row i+1, issue row i+2 ->(f)
    int r0 = min(HW-1, max(0, s + 0));
    int r1 = min(HW-1, max(0, s + 1));
    const float4* rp0 = (const float4*)(P + (size_t)r0 * HW);
    const float4* rp1 = (const float4*)(P + (size_t)r1 * HW);
    float4 c0 = rp0[2*l], c1 = rp0[2*l+1];
    float4 n0 = rp1[2*l], n1 = rp1[2*l+1];
    float4 tc0, tc1, tn0, tn1;   // tgt pipeline (valid when window reached)

#pragma unroll 4
    for (int i = 0; i < 28; ++i){
        // issue prefetches for row i+2
        float4 f0, f1, tf0, tf1;
        if (i < 26){
            int rn = min(HW-1, max(0, s + i + 2));
            const float4* rp = (const float4*)(P + (size_t)rn * HW);
            f0 = rp[2*l]; f1 = rp[2*l+1];
        }
        if (i + 2 >= 6 && i + 2 < 22){
            const float4* tp = (const float4*)(T + (size_t)(s + i + 2) * HW);
            tf0 = tp[2*l]; tf1 = tp[2*l+1];
        }

        const float p0=c0.x,p1v=c0.y,p2v=c0.z,p3=c0.w,
                    p4=c1.x,p5=c1.y,p6=c1.z,p7=c1.w;

        // pix term: wave owns input rows s+6..s+21
        if (i >= 6 && i < 22){
            pix_acc += fabsf(p0-tc0.x)+fabsf(p1v-tc0.y)+fabsf(p2v-tc0.z)+fabsf(p3-tc0.w)
                     + fabsf(p4-tc1.x)+fabsf(p5-tc1.y)+fabsf(p6-tc1.z)+fabsf(p7-tc1.w);
        }

        // horizontal halo via shuffles: cols 8l-6..8l-1 and 8l+8..8l+13
        float Lm6 = __shfl_up(p2v,1,64), Lm5 = __shfl_up(p3,1,64),
              Lm4 = __shfl_up(p4,1,64),  Lm3 = __shfl_up(p5,1,64),
              Lm2 = __shfl_up(p6,1,64),  Lm1 = __shfl_up(p7,1,64);
        float R8  = __shfl_down(p0,1,64), R9  = __shfl_down(p1v,1,64),
              R10 = __shfl_down(p2v,1,64),R11 = __shfl_down(p3,1,64),
              R12 = __shfl_down(p4,1,64), R13 = __shfl_down(p5,1,64);
        if (l == 0){ Lm6=p0; Lm5=p0; Lm4=p0; Lm3=p0; Lm2=p0; Lm1=p0; }
        if (l == 63){ R8=p7; R9=p7; R10=p7; R11=p7; R12=p7; R13=p7; }

        float w20[20] = {Lm6,Lm5,Lm4,Lm3,Lm2,Lm1,p0,p1v,p2v,p3,p4,p5,p6,p7,
                         R8,R9,R10,R11,R12,R13};
        float h0 = 0.f, h1 = 0.f;
#pragma unroll
        for (int k = 0; k < 16; ++k){
            h0 += wt[k]*w20[k];
            h1 += wt[k]*w20[k+4];
        }

        // vertical accumulate into the 4 output rows this wave owns
#pragma unroll
        for (int q = 0; q < 4; ++q){
            int k = i - 4*q;
            if (k >= 0 && k < 16){
                acc[q][0] += wt[k]*h0;
                acc[q][1] += wt[k]*h1;
            }
        }

        // rotate pipelines
        c0=n0; c1=n1; n0=f0; n1=f1;
        tc0=tn0; tc1=tn1; tn0=tf0; tn1=tf1;
    }

    // lr term: lane l holds out cols 2l,2l+1 for rows o0..o0+3
#pragma unroll
    for (int q = 0; q < 4; ++q){
        const float2 lv = *(const float2*)(L + (size_t)(o0+q)*OUTW + 2*l);
        lr_acc += fabsf(acc[q][0]-lv.x) + fabsf(acc[q][1]-lv.y);
    }

    // intra-wave reduction, one slot per wave (no atomics, no init needed)
#pragma unroll
    for (int off = 32; off > 0; off >>= 1){
        pix_acc += __shfl_down(pix_acc, off, 64);
        lr_acc  += __shfl_down(lr_acc,  off, 64);
    }
    if (l == 0){
        const int slot = (blockIdx.x << 2) + w;
        part[slot]         = (double)pix_acc;
        part[NPART + slot] = (double)lr_acc;
    }
}

__global__ __launch_bounds__(256) void k3(const double* __restrict__ part,
                                          float* __restrict__ out){
    const int t = threadIdx.x;
    double v1 = 0.0, v2 = 0.0;
    for (int i = t; i < NPART; i += 256){
        v1 += part[i];
        v2 += part[NPART + i];
    }
#pragma unroll
    for (int off = 32; off > 0; off >>= 1){
        v1 += __shfl_down(v1, off, 64);
        v2 += __shfl_down(v2, off, 64);
    }
    __shared__ double s1[4], s2[4];
    const int lane = t & 63, wid = t >> 6;
    if (lane == 0){ s1[wid] = v1; s2[wid] = v2; }
    __syncthreads();
    if (t == 0){
        double S1 = s1[0]+s1[1]+s1[2]+s1[3];
        double S2 = s2[0]+s2[1]+s2[2]+s2[3];
        float pix     = (float)(S1 / (double)N_HR);
        float lr_term = (float)(S2 / (double)N_LR);
        float pair    = 0.f;
        float consist = 1.0f * lr_term + 1.0f * pair;   // LAM_LR, LAM_PAIR
        float total   = pix + 0.1f * consist;           // LAM_CONSIST
        out[0] = total; out[1] = pix; out[2] = consist; out[3] = lr_term; out[4] = pair;
    }
}

extern "C" void kernel_launch(void* const* d_in, const int* in_sizes, int n_in,
                              void* d_out, int out_size, void* d_ws, size_t ws_size,
                              hipStream_t stream){
    const float* pred = (const float*)d_in[0];
    const float* tgt  = (const float*)d_in[1];
    const float* lrr  = (const float*)d_in[2];
    float* out = (float*)d_out;

    double* part = (double*)d_ws;   // 2 * 3072 doubles = 48 KB, every slot written

    kmain<<<NIMG*8, 256, 0, stream>>>(pred, tgt, lrr, part);
    k3<<<1, 256, 0, stream>>>(part, out);
}